// Round 1
// baseline (245.523 us; speedup 1.0000x reference)
//
#include <hip/hip_runtime.h>

#define LPC_N 32
#define LPC_EPS 1e-5f

// One thread = ONE frame. Working set: ac[33] + lp[32] = 65 floats + temps
// ~= 90 VGPRs, vs the 2-frame/float2 version whose 130-reg live set forced
// the compiler into AGPR shadowing (256-reg waves -> 2 waves/SIMD, 27% occ).
// __launch_bounds__(256, 5): cap allocator at ~102 regs -> >=5 waves/SIMD.
__global__ __launch_bounds__(256, 5) void levinson_kernel(
    const float* __restrict__ pAC,   // [N+1, T]
    float* __restrict__ out,         // [N, T]
    int T)
{
    int t = blockIdx.x * blockDim.x + threadIdx.x;   // frame index
    if (t >= T) return;

    // 33 coalesced dword loads (4 B/lane, 256 B/wave), all independent ->
    // full memory-level parallelism up front.
    float ac[LPC_N + 1];
#pragma unroll
    for (int i = 0; i <= LPC_N; ++i) {
        ac[i] = pAC[(size_t)i * T + t];
    }

    float lp[LPC_N];
    float E = ac[0];

#pragma unroll
    for (int i = 0; i < LPC_N; ++i) {
        // rcp issued first: latency hides under the dot product.
        float invE = __builtin_amdgcn_rcpf(E);

        // acc = ac[i+1] + sum_{j<i} lp[j]*ac[i-j], two independent FMA chains.
        float s0 = ac[i + 1];
        float s1 = 0.0f;
#pragma unroll
        for (int j = 0; j + 1 < i; j += 2) {
            s0 += lp[j]     * ac[i - j];
            s1 += lp[j + 1] * ac[i - j - 1];
        }
        if (i & 1) {                    // leftover j = i-1 when i is odd
            s0 += lp[i - 1] * ac[1];
        }
        float acc = s0 + s1;

        float ki = acc * invE;
        float c  = fmaxf(1.0f - ki * ki, LPC_EPS);
        E *= c;

        // lp[j] = lp[j] - ki*lp[i-1-j] from OLD lp: pairwise swap update.
#pragma unroll
        for (int j = 0; j < i - 1 - j; ++j) {
            float a = lp[j];
            float b = lp[i - 1 - j];
            lp[j]         = a - ki * b;
            lp[i - 1 - j] = b - ki * a;
        }
        if (i & 1) {
            int m = (i - 1) >> 1;       // self-paired middle element
            lp[m] = lp[m] - ki * lp[m];
        }
        lp[i] = -ki;
    }

    // 32 coalesced non-temporal stores: output is write-once/never-read,
    // keep it out of L2/L3 so the LLC keeps serving the input re-reads.
#pragma unroll
    for (int i = 0; i < LPC_N; ++i) {
        __builtin_nontemporal_store(lp[i], &out[(size_t)i * T + t]);
    }
}

extern "C" void kernel_launch(void* const* d_in, const int* in_sizes, int n_in,
                              void* d_out, int out_size, void* d_ws, size_t ws_size,
                              hipStream_t stream)
{
    const float* pAC = (const float*)d_in[0];
    float* out = (float*)d_out;
    int T = in_sizes[0] / (LPC_N + 1);   // 1048576

    int block = 256;
    int grid = (T + block - 1) / block;  // 4096 blocks
    levinson_kernel<<<grid, block, 0, stream>>>(pAC, out, T);
}

// Round 2
// 244.906 us; speedup vs baseline: 1.0025x; 1.0025x over previous
//
#include <hip/hip_runtime.h>

#define LPC_N 32
#define LPC_EPS 1e-5f
#define FRAMES 4          // frames per thread (2-stage ping-pong pipeline)

// Issue all 33 row loads for one frame (coalesced dword, 256 B/wave/row).
__device__ __forceinline__ void load_ac(float ac[LPC_N + 1],
                                        const float* __restrict__ pAC,
                                        int T, int t)
{
#pragma unroll
    for (int k = 0; k <= LPC_N; ++k) {
        ac[k] = pAC[(size_t)k * T + t];
    }
}

// Levinson recursion for one frame + 32 nontemporal stores.
__device__ __forceinline__ void levinson_compute_store(
    const float ac[LPC_N + 1], float* __restrict__ out, int T, int t)
{
    float lp[LPC_N];
    float E = ac[0];

#pragma unroll
    for (int i = 0; i < LPC_N; ++i) {
        // rcp issued first: latency hides under the dot product.
        float invE = __builtin_amdgcn_rcpf(E);

        // acc = ac[i+1] + sum_{j<i} lp[j]*ac[i-j], two independent FMA chains.
        float s0 = ac[i + 1];
        float s1 = 0.0f;
#pragma unroll
        for (int j = 0; j + 1 < i; j += 2) {
            s0 += lp[j]     * ac[i - j];
            s1 += lp[j + 1] * ac[i - j - 1];
        }
        if (i & 1) {                    // leftover j = i-1 when i is odd
            s0 += lp[i - 1] * ac[1];
        }
        float acc = s0 + s1;

        float ki = acc * invE;
        float c  = fmaxf(1.0f - ki * ki, LPC_EPS);
        E *= c;

        // lp[j] = lp[j] - ki*lp[i-1-j] from OLD lp: pairwise swap update.
#pragma unroll
        for (int j = 0; j < i - 1 - j; ++j) {
            float a = lp[j];
            float b = lp[i - 1 - j];
            lp[j]         = a - ki * b;
            lp[i - 1 - j] = b - ki * a;
        }
        if (i & 1) {
            int m = (i - 1) >> 1;       // self-paired middle element
            lp[m] = lp[m] - ki * lp[m];
        }
        lp[i] = -ki;
    }

    // Nontemporal: output is write-once/never-read; stores drain under the
    // NEXT frame's compute (no vmcnt wait until lp regs are rewritten).
#pragma unroll
    for (int i = 0; i < LPC_N; ++i) {
        __builtin_nontemporal_store(lp[i], &out[(size_t)i * T + t]);
    }
}

// Each thread pipelines FRAMES frames: loads of frame f+1 are issued BEFORE
// the compute of frame f, so HBM reads stream under the recursion and the
// phase-locked load/compute/store oscillation (the round-1 bottleneck:
// HBM 28% and VALU 36% both idle half the time) is broken structurally.
// Working set: acA[33] + acB[33] + lp[32] + temps ~= 110 regs -> cap at 128
// via __launch_bounds__(256, 4): 4 waves/SIMD, 16 waves/CU, exactly one
// resident generation (1024 blocks on 256 CUs).
__global__ __launch_bounds__(256, 4) void levinson_kernel(
    const float* __restrict__ pAC,   // [N+1, T]
    float* __restrict__ out,         // [N, T]
    int T, int nthreads)
{
    int t0 = blockIdx.x * blockDim.x + threadIdx.x;
    if (t0 >= nthreads) return;
    const int s = nthreads;          // frame stride between pipeline stages

    float acA[LPC_N + 1];
    float acB[LPC_N + 1];

    load_ac(acA, pAC, T, t0);                    // frame 0
    load_ac(acB, pAC, T, t0 + s);                // prefetch frame 1
    levinson_compute_store(acA, out, T, t0);     // compute 0 (waits acA only)

    load_ac(acA, pAC, T, t0 + 2 * s);            // prefetch frame 2
    levinson_compute_store(acB, out, T, t0 + s); // compute 1

    load_ac(acB, pAC, T, t0 + 3 * s);            // prefetch frame 3
    levinson_compute_store(acA, out, T, t0 + 2 * s);

    levinson_compute_store(acB, out, T, t0 + 3 * s);
}

extern "C" void kernel_launch(void* const* d_in, const int* in_sizes, int n_in,
                              void* d_out, int out_size, void* d_ws, size_t ws_size,
                              hipStream_t stream)
{
    const float* pAC = (const float*)d_in[0];
    float* out = (float*)d_out;
    int T = in_sizes[0] / (LPC_N + 1);   // 1048576

    int nthreads = T / FRAMES;           // 262144 (T = 2^20, divisible)
    int block = 256;
    int grid = (nthreads + block - 1) / block;   // 1024 blocks
    levinson_kernel<<<grid, block, 0, stream>>>(pAC, out, T, nthreads);
}

// Round 3
// 243.640 us; speedup vs baseline: 1.0077x; 1.0052x over previous
//
#include <hip/hip_runtime.h>

#define LPC_N 32
#define LPC_EPS 1e-5f
#define NREG 17                       // ac[0..16] live in VGPRs (hot lags)
#define NLDS (LPC_N + 1 - NREG)       // ac[17..32] staged in LDS (cold lags)

// Round-2 post-mortem: double-buffered prefetch forced AGPR shadowing and
// serialized on vmcnt (90 -> 128 us). Root cause of the 90 us plateau is the
// 65-float working set: compiler sinks high-lag loads mid-recursion and waves
// eat global latency at ~4.6 waves/SIMD. Fix: split the working set.
//   - ac[0..16] (used 16..32x each) stay in VGPRs.
//   - ac[17..32] (used 1..16x each) live in per-wave LDS: 4 KB/wave,
//     bank = lane%32 -> 2-way access = conflict-free, ~100 cy latency,
//     read on the DS pipe (doesn't consume VALU issue).
// Live regs: lp[32] + ac[17] + temps ~= 60 -> __launch_bounds__(256,7)
// (73-reg cap) gives ~28 waves/CU with no AGPR shadow and no scratch.
__global__ __launch_bounds__(256, 7) void levinson_kernel(
    const float* __restrict__ pAC,   // [N+1, T]
    float* __restrict__ out,         // [N, T]
    int T)
{
    __shared__ float smem[4 * NLDS * 64];   // 16 KB/block, per-wave chunks

    const int tid  = threadIdx.x;
    const int lane = tid & 63;
    const int wv   = tid >> 6;
    const int t    = blockIdx.x * blockDim.x + tid;
    if (t >= T) return;

    float* wbuf = smem + wv * (NLDS * 64);

    // Stage high lags into per-wave LDS. Wave-private -> no __syncthreads.
    // Transient hi[] regs overlap only with the (not-yet-live) lp array.
    {
        float hi[NLDS];
#pragma unroll
        for (int k = 0; k < NLDS; ++k)
            hi[k] = pAC[(size_t)(NREG + k) * T + t];
#pragma unroll
        for (int k = 0; k < NLDS; ++k)
            wbuf[k * 64 + lane] = hi[k];
    }

    // Hot lags -> registers (coalesced dword loads, 256 B/wave/row).
    float ac[NREG];
#pragma unroll
    for (int k = 0; k < NREG; ++k)
        ac[k] = pAC[(size_t)k * T + t];

    // All indices below are compile-time constants (fully unrolled), so this
    // folds to either a VGPR read or a ds_read_b32 with an imm offset.
    auto AC = [&](int m) -> float {
        return (m < NREG) ? ac[m] : wbuf[(m - NREG) * 64 + lane];
    };

    float lp[LPC_N];
    float E = ac[0];

#pragma unroll
    for (int i = 0; i < LPC_N; ++i) {
        // rcp issued first: latency hides under the dot product.
        float invE = __builtin_amdgcn_rcpf(E);

        // acc = ac[i+1] + sum_{j<i} lp[j]*ac[i-j], two independent FMA chains.
        float s0 = AC(i + 1);
        float s1 = 0.0f;
#pragma unroll
        for (int j = 0; j + 1 < i; j += 2) {
            s0 += lp[j]     * AC(i - j);
            s1 += lp[j + 1] * AC(i - j - 1);
        }
        if (i & 1) {                    // leftover j = i-1 when i is odd
            s0 += lp[i - 1] * ac[1];
        }
        float acc = s0 + s1;

        float ki = acc * invE;
        float c  = fmaxf(1.0f - ki * ki, LPC_EPS);
        E *= c;

        // lp[j] = lp[j] - ki*lp[i-1-j] from OLD lp: pairwise swap update.
#pragma unroll
        for (int j = 0; j < i - 1 - j; ++j) {
            float a = lp[j];
            float b = lp[i - 1 - j];
            lp[j]         = a - ki * b;
            lp[i - 1 - j] = b - ki * a;
        }
        if (i & 1) {
            int m = (i - 1) >> 1;       // self-paired middle element
            lp[m] = lp[m] - ki * lp[m];
        }
        lp[i] = -ki;
    }

    // Nontemporal coalesced stores: write-once/never-read, keep out of LLC.
#pragma unroll
    for (int i = 0; i < LPC_N; ++i) {
        __builtin_nontemporal_store(lp[i], &out[(size_t)i * T + t]);
    }
}

extern "C" void kernel_launch(void* const* d_in, const int* in_sizes, int n_in,
                              void* d_out, int out_size, void* d_ws, size_t ws_size,
                              hipStream_t stream)
{
    const float* pAC = (const float*)d_in[0];
    float* out = (float*)d_out;
    int T = in_sizes[0] / (LPC_N + 1);   // 1048576

    int block = 256;
    int grid = (T + block - 1) / block;  // 4096 blocks
    levinson_kernel<<<grid, block, 0, stream>>>(pAC, out, T);
}